// Round 6
// baseline (794.299 us; speedup 1.0000x reference)
//
#include <hip/hip_runtime.h>
#include <hip/hip_bf16.h>

#define N_TEXT 80000
#define NTOT   100000
#define NE     200000
#define EMB    256
#define HID    256
#define VMOT   17
#define MDIM   64
#define KTOK   4

typedef unsigned short u16;
typedef unsigned int   u32;
typedef short short8 __attribute__((ext_vector_type(8)));
typedef float f32x4 __attribute__((ext_vector_type(4)));

// ---------------- workspace layout (float offsets) ----------------
#define O_INVF 0                    // [NTOT]
#define O_INVR (NTOT)
#define O_POS  (2*NTOT)             // [NTOT*10]
#define O_ADJ  (12*NTOT)            // [289] (pad 512)
#define O_HTB  (12*NTOT + 512)      // u16[17*64] (pad 576 floats)
#define O_GATE (12*NTOT + 1088)
#define O_CVEC (12*NTOT + 1104)
#define O_NME  (12*NTOT + 1360)     // u16[NTOT*64]
#define O_WSW  (O_NME + NTOT*32)    // swizzled bf16 weight blob
#define ZERO_FLOATS (12*NTOT + 512)
#define Z4 (ZERO_FLOATS/4)

// blob layout (u16): [chunk][global n-tile j 0..15][lane 0..63][8]
// chunk index: A=0..19, B=20, C=21..30, D=31..38
#define GA 20480
#define GB 1024
#define GC 10240
#define GD 8192
#define GTOT (GA+GB+GC+GD)

__device__ __forceinline__ u16 f2b(float f) {   // fp32 -> bf16 RNE
  unsigned u = __float_as_uint(f);
  return (u16)((u + 0x7fffu + ((u >> 16) & 1u)) >> 16);
}
__device__ __forceinline__ float b2f(u16 v) {
  return __uint_as_float(((unsigned)v) << 16);
}
__device__ __forceinline__ short8 pack8f(const float* f) {
  union { u32 u[4]; short8 s; } o;
#pragma unroll
  for (int i = 0; i < 4; i++) {
    __hip_bfloat162 b = __float22bfloat162_rn(float2{f[2*i], f[2*i+1]});
    o.u[i] = *reinterpret_cast<u32*>(&b);
  }
  return o.s;
}

// ---------------- L1: zero + swizzled weight pack ----------------
__global__ void k_prep(const float* __restrict__ nh_w, const float* __restrict__ pos_w,
                       const float* __restrict__ st_w, const float* __restrict__ pw1,
                       float* __restrict__ ws) {
  int g = blockIdx.x * blockDim.x + threadIdx.x;
  if (g < Z4) { ((float4*)ws)[g] = make_float4(0.f, 0.f, 0.f, 0.f); return; }
  g -= Z4;
  if (g >= GTOT) return;
  int l, phase;
  if (g < GA) { l = g; phase = 0; }
  else if (g < GA + GB) { l = g - GA; phase = 1; }
  else if (g < GA + GB + GC) { l = g - GA - GB; phase = 2; }
  else { l = g - GA - GB - GC; phase = 3; }
  int c = l >> 10, r = l & 1023;
  int w = r >> 8, nt = (r >> 6) & 3, ln = r & 63;
  int col = w*64 + nt*16 + (ln & 15);
  int k0  = c*32 + ((ln >> 4) << 3);
  float f[8];
#pragma unroll
  for (int j = 0; j < 8; j++) {
    int k = k0 + j;
    float v = 0.f;
    if (phase == 0)      v = nh_w[k*256 + col];
    else if (phase == 1) { if (k < 10) v = pos_w[k*256 + col];
                           else if (k >= 16 && k < 26) v = pos_w[(k-6)*256 + col]; }
    else if (phase == 2) v = st_w[k*256 + col];
    else                 v = pw1[(256 + k)*256 + col];
    f[j] = v;
  }
  ((short8*)((u16*)(ws + O_WSW)))[g] = pack8f(f);
}

// ---------------- L2: deg + DDE round-1 + motif adjacency ----------------
__global__ void k_deg_dde1_adj(const int* __restrict__ h_id, const int* __restrict__ t_id,
                               const float* __restrict__ topic,
                               const int* __restrict__ tids, const float* __restrict__ twts,
                               float* __restrict__ ws) {
  __shared__ float sadj[4*304];
  for (int i = threadIdx.x; i < 4*304; i += blockDim.x) sadj[i] = 0.f;
  __syncthreads();
  int wbase = (threadIdx.x >> 6) * 304;
  int e = blockIdx.x * blockDim.x + threadIdx.x;
  if (e < NE) {
    int h = h_id[e], t = t_id[e];
    atomicAdd(&ws[O_INVF + t], 1.0f);
    atomicAdd(&ws[O_INVR + h], 1.0f);
    float hx = topic[2*h], hy = topic[2*h + 1];
    float tx = topic[2*t], ty = topic[2*t + 1];
    if (hx != 0.f) atomicAdd(&ws[O_POS + t*10 + 2], hx);
    if (hy != 0.f) atomicAdd(&ws[O_POS + t*10 + 3], hy);
    if (tx != 0.f) atomicAdd(&ws[O_POS + h*10 + 6], tx);
    if (ty != 0.f) atomicAdd(&ws[O_POS + h*10 + 7], ty);
    int id[KTOK]; float w[KTOK];
#pragma unroll
    for (int k = 0; k < KTOK; k++) { id[k] = tids[e*KTOK + k]; w[k] = twts[e*KTOK + k]; }
#pragma unroll
    for (int i = 0; i < KTOK; i++)
#pragma unroll
      for (int j = 0; j < KTOK; j++) {
        float c = w[i] * w[j];
        if (id[i] > 0 && id[j] > 0 && c > 0.f)
          atomicAdd(&sadj[wbase + id[i]*VMOT + id[j]], c);
      }
  }
  __syncthreads();
  for (int i = threadIdx.x; i < VMOT*VMOT; i += blockDim.x) {
    float v = sadj[i] + sadj[304 + i] + sadj[608 + i] + sadj[912 + i];
    if (v != 0.f) atomicAdd(&ws[O_ADJ + i], v);
  }
}

// ---------------- L3: prep_nodes + motif GNN + gate/cvec ----------------
#define NPN_BLOCKS ((NTOT + 255)/256)
__global__ void k_pnm(const float* __restrict__ topic, const float* __restrict__ mo,
                      const float* __restrict__ gsw, const float* __restrict__ gsb,
                      const float* __restrict__ gmw, const float* __restrict__ gmb,
                      const float* __restrict__ q, const float* __restrict__ gate_w,
                      const float* __restrict__ gate_b, const float* __restrict__ pw1,
                      const float* __restrict__ pb1, float* __restrict__ ws) {
  int t = threadIdx.x;
  if (blockIdx.x < NPN_BLOCKS) {
    int n = blockIdx.x * 256 + t;
    if (n >= NTOT) return;
    float invf = 1.0f / fmaxf(ws[O_INVF + n], 1.0f);
    float invr = 1.0f / fmaxf(ws[O_INVR + n], 1.0f);
    ws[O_INVF + n] = invf;
    ws[O_INVR + n] = invr;
    float* p = &ws[O_POS + n*10];
    p[0] = topic[2*n]; p[1] = topic[2*n + 1];
    p[2] *= invf; p[3] *= invf;
    p[6] *= invr; p[7] *= invr;
  } else if (blockIdx.x == NPN_BLOCKS) {
    __shared__ float A[VMOT*VMOT];
    __shared__ float Bm[VMOT*VMOT];
    __shared__ float inv_row[VMOT];
    __shared__ float smo[VMOT*MDIM];
    __shared__ float sm[VMOT*MDIM];
    for (int i = t; i < VMOT*VMOT; i += 256) A[i] = ws[O_ADJ + i];
    for (int i = t; i < VMOT*MDIM; i += 256) smo[i] = mo[i];
    __syncthreads();
    for (int i = t; i < VMOT*VMOT; i += 256) {
      int r = i / VMOT, c = i % VMOT;
      float v = 0.5f * (A[i] + A[c*VMOT + r]) + (r == c ? 1.f : 0.f);
      if (r == 0 || c == 0) v = (r == 0 && c == 0) ? 1.f : 0.f;
      Bm[i] = v;
    }
    __syncthreads();
    if (t < VMOT) {
      float s = 0.f;
      for (int c = 0; c < VMOT; c++) s += Bm[t*VMOT + c];
      inv_row[t] = 1.f / fmaxf(s, 1e-8f);
    }
    __syncthreads();
    for (int i = t; i < VMOT*MDIM; i += 256) {
      int v = i / MDIM, d = i % MDIM;
      float s = 0.f;
      for (int u = 0; u < VMOT; u++) s += Bm[v*VMOT + u] * smo[u*MDIM + d];
      sm[i] = s * inv_row[v];
    }
    __syncthreads();
    for (int i = t; i < VMOT*MDIM; i += 256) {
      int v = i / MDIM, d = i % MDIM;
      float a = gsb[d] + gmb[d];
      for (int m = 0; m < MDIM; m++)
        a += smo[v*MDIM + m] * gsw[m*MDIM + d] + sm[v*MDIM + m] * gmw[m*MDIM + d];
      ((u16*)(ws + O_HTB))[i] = f2b(smo[i] + fmaxf(a, 0.f));
    }
  } else {
    __shared__ float sq[EMB];
    __shared__ float red[3];
    sq[t] = q[t];
    if (t < 3) red[t] = 0.f;
    __syncthreads();
    float s = pb1[t];
    for (int i = 0; i < EMB; i++) s += sq[i] * pw1[i*HID + t];
    ws[O_CVEC + t] = s;
    atomicAdd(&red[0], sq[t] * gate_w[t*3 + 0]);
    atomicAdd(&red[1], sq[t] * gate_w[t*3 + 1]);
    atomicAdd(&red[2], sq[t] * gate_w[t*3 + 2]);
    __syncthreads();
    if (t == 0) {
      float l0 = red[0] + gate_b[0], l1 = red[1] + gate_b[1], l2 = red[2] + gate_b[2];
      float mx = fmaxf(l0, fmaxf(l1, l2));
      float e0 = expf(l0 - mx), e1 = expf(l1 - mx), e2 = expf(l2 - mx);
      float inv = 1.f / (e0 + e1 + e2);
      ws[O_GATE + 0] = e0 * inv; ws[O_GATE + 1] = e1 * inv; ws[O_GATE + 2] = e2 * inv;
    }
  }
}

// ---------------- L4: DDE round-2 scatter ----------------
__global__ void k_dde2(const int* __restrict__ h_id, const int* __restrict__ t_id,
                       float* __restrict__ ws) {
  int e = blockIdx.x * blockDim.x + threadIdx.x;
  if (e >= NE) return;
  int h = h_id[e], t = t_id[e];
  float a = ws[O_POS + h*10 + 2], b = ws[O_POS + h*10 + 3];
  float c = ws[O_POS + t*10 + 6], d = ws[O_POS + t*10 + 7];
  if (a != 0.f) atomicAdd(&ws[O_POS + t*10 + 4], a);
  if (b != 0.f) atomicAdd(&ws[O_POS + t*10 + 5], b);
  if (c != 0.f) atomicAdd(&ws[O_POS + h*10 + 8], c);
  if (d != 0.f) atomicAdd(&ws[O_POS + h*10 + 9], d);
}

// ---------------- L5: round-2 scale + node motif emb (bf16) ----------------
__global__ void k_scale_nme(const int* __restrict__ nids, const float* __restrict__ nwts,
                            float* __restrict__ ws) {
  __shared__ u16 sht[VMOT*MDIM];
  for (int i = threadIdx.x; i < (VMOT*MDIM)/2; i += blockDim.x)
    ((u32*)sht)[i] = ((const u32*)(ws + O_HTB))[i];
  __syncthreads();
  int gid = blockIdx.x * blockDim.x + threadIdx.x;
  if (gid < NTOT) {
    float invf = ws[O_INVF + gid], invr = ws[O_INVR + gid];
    float* p = &ws[O_POS + gid*10];
    p[4] *= invf; p[5] *= invf;
    p[8] *= invr; p[9] *= invr;
  }
  if (gid >= NTOT * 8) return;
  int n = gid >> 3, d0 = (gid & 7) * 8;
  int4   iv = ((const int4*)nids)[n];
  float4 wv = ((const float4*)nwts)[n];
  float f[8];
#pragma unroll
  for (int j = 0; j < 8; j++) {
    f[j] = wv.x * b2f(sht[iv.x*MDIM + d0 + j]) + wv.y * b2f(sht[iv.y*MDIM + d0 + j])
         + wv.z * b2f(sht[iv.z*MDIM + d0 + j]) + wv.w * b2f(sht[iv.w*MDIM + d0 + j]);
  }
  ((short8*)((u16*)(ws + O_NME)))[gid] = pack8f(f);
}

// ---------------- L6: barrier-FREE MFMA edge kernel (wave-per-M-slice) -----
// Each wave owns 16 edges x all 256 cols. A-frags gathered per-lane directly
// in MFMA A-layout (lane&15 = edge, quad = k-segment); B-frags direct from
// blob (identical addrs across waves -> L1 broadcast). C->A transpose via
// PRIVATE per-wave LDS region (stride 264 -> conflict-free b128 reads).
// ZERO __syncthreads in the whole kernel.
#define TSTR 264
__global__ __launch_bounds__(256, 4) void k_edge_mfma(
    const int* __restrict__ h_id, const int* __restrict__ r_id, const int* __restrict__ t_id,
    const float* __restrict__ ent, const float* __restrict__ rel, const float* __restrict__ nte,
    const int* __restrict__ tids, const float* __restrict__ twts,
    const float* __restrict__ nh_b, const float* __restrict__ pos_b,
    const float* __restrict__ st_b, const float* __restrict__ pw2,
    const float* __restrict__ pb2,
    const float* __restrict__ ws, float* __restrict__ out) {
  __shared__ __align__(16) u16 sT[4*16*TSTR];   // 33792 B, per-wave 16xTSTR

  const int tid = threadIdx.x;
  const int wv = tid >> 6, ln = tid & 63;
  const int lm = ln & 15, lq = ln >> 4;
  const int e0 = blockIdx.x * 64;
  const int me = e0 + wv*16 + lm;               // this lane's edge row
  u16* myT = &sT[wv*16*TSTR];

  const int hN = h_id[me], tN = t_id[me];
  const float g0 = ws[O_GATE + 0], g1 = ws[O_GATE + 1], g2 = ws[O_GATE + 2];
  const u16* blob = (const u16*)(ws + O_WSW);
  const u16* nmeb = (const u16*)(ws + O_NME);
  const u16* htb  = (const u16*)(ws + O_HTB);

  f32x4 acc[16];
#pragma unroll
  for (int j = 0; j < 16; j++) acc[j] = (f32x4){0.f, 0.f, 0.f, 0.f};

  auto mfma_all = [&](int bc, short8 av) {
#pragma unroll
    for (int j = 0; j < 16; j++) {
      short8 bv = *(const short8*)&blob[(size_t)bc*8192 + j*512 + ln*8];
      acc[j] = __builtin_amdgcn_mfma_f32_16x16x32_bf16(av, bv, acc[j], 0, 0, 0);
    }
  };
  auto packf4 = [&](float4 v0, float4 v1) {
    float f[8] = {v0.x, v0.y, v0.z, v0.w, v1.x, v1.y, v1.z, v1.w};
    return pack8f(f);
  };

  // ======== phase A: K=640 = [h_e[h] | h_e[t] | nme[h] | nme[t]] ========
  {
    const float* hbase = (hN < N_TEXT) ? &ent[(size_t)hN*256] : nte;
    const float* tbase = (tN < N_TEXT) ? &ent[(size_t)tN*256] : nte;
#pragma unroll 2
    for (int c = 0; c < 8; c++) {
      const float* p = hbase + c*32 + lq*8;
      mfma_all(c, packf4(*(const float4*)p, *(const float4*)(p + 4)));
    }
#pragma unroll 2
    for (int c = 0; c < 8; c++) {
      const float* p = tbase + c*32 + lq*8;
      mfma_all(8 + c, packf4(*(const float4*)p, *(const float4*)(p + 4)));
    }
#pragma unroll
    for (int c = 0; c < 2; c++)
      mfma_all(16 + c, *(const short8*)&nmeb[(size_t)hN*64 + c*32 + lq*8]);
#pragma unroll
    for (int c = 0; c < 2; c++)
      mfma_all(18 + c, *(const short8*)&nmeb[(size_t)tN*64 + c*32 + lq*8]);
  }
  // epilogue A: myT = g0*relu(acc + nh_b)   (C-layout: row=lq*4+r, col=j*16+lm)
#pragma unroll
  for (int j = 0; j < 16; j++) {
    float bb = nh_b[j*16 + lm];
#pragma unroll
    for (int r = 0; r < 4; r++) {
      myT[(lq*4 + r)*TSTR + j*16 + lm] = f2b(g0 * fmaxf(acc[j][r] + bb, 0.f));
      acc[j][r] = 0.f;
    }
  }

  // ======== phase B: K=32 = [pos[h](10) pad6 | pos[t](10) pad6] ========
  {
    int node = (lq < 2) ? hN : tN;
    int k0 = (lq & 1) * 8;
    const float* p = &ws[O_POS + (size_t)node*10 + k0];
    float2 v0 = *(const float2*)p,       v1 = *(const float2*)(p + 2);
    float2 v2 = *(const float2*)(p + 4), v3 = *(const float2*)(p + 6);
    float f[8] = {v0.x, v0.y, v1.x, v1.y, v2.x, v2.y, v3.x, v3.y};
#pragma unroll
    for (int j = 0; j < 8; j++) if (k0 + j >= 10) f[j] = 0.f;
    mfma_all(20, pack8f(f));
  }
#pragma unroll
  for (int j = 0; j < 16; j++) {
    float bb = pos_b[j*16 + lm];
#pragma unroll
    for (int r = 0; r < 4; r++) {
      u16* p = &myT[(lq*4 + r)*TSTR + j*16 + lm];
      *p = f2b(b2f(*p) + g1 * fmaxf(acc[j][r] + bb, 0.f));
      acc[j][r] = 0.f;
    }
  }

  // ======== phase C: K=320 = [rel[r] | triple_motif_emb] ========
  {
    const int rN = r_id[me];
    const float* rbase = &rel[(size_t)rN*256];
#pragma unroll 2
    for (int c = 0; c < 8; c++) {
      const float* p = rbase + c*32 + lq*8;
      mfma_all(21 + c, packf4(*(const float4*)p, *(const float4*)(p + 4)));
    }
    int4   tiv = ((const int4*)tids)[me];
    float4 twv = ((const float4*)twts)[me];
#pragma unroll
    for (int c = 0; c < 2; c++) {
      int d0 = c*32 + lq*8;
      short8 h0 = *(const short8*)&htb[tiv.x*64 + d0];
      short8 h1 = *(const short8*)&htb[tiv.y*64 + d0];
      short8 h2 = *(const short8*)&htb[tiv.z*64 + d0];
      short8 h3 = *(const short8*)&htb[tiv.w*64 + d0];
      float f[8];
#pragma unroll
      for (int j = 0; j < 8; j++)
        f[j] = twv.x * b2f((u16)h0[j]) + twv.y * b2f((u16)h1[j])
             + twv.z * b2f((u16)h2[j]) + twv.w * b2f((u16)h3[j]);
      mfma_all(29 + c, pack8f(f));
    }
  }
#pragma unroll
  for (int j = 0; j < 16; j++) {
    float bb = st_b[j*16 + lm];
#pragma unroll
    for (int r = 0; r < 4; r++) {
      u16* p = &myT[(lq*4 + r)*TSTR + j*16 + lm];
      *p = f2b(b2f(*p) + g2 * fmaxf(acc[j][r] + bb, 0.f));
      acc[j][r] = 0.f;
    }
  }

  // ======== phase D: hidden = fused @ pw1[256:512] ========
  // same-wave LDS dependence only -> compiler lgkmcnt, no barrier
#pragma unroll 2
  for (int c = 0; c < 8; c++) {
    short8 av = *(const short8*)&myT[lm*TSTR + c*32 + lq*8];
    mfma_all(31 + c, av);
  }

  // ======== epilogue: out = relu(hidden + cvec) @ pw2 + pb2 ========
  {
    float s[4] = {0.f, 0.f, 0.f, 0.f};
#pragma unroll
    for (int j = 0; j < 16; j++) {
      float cv = ws[O_CVEC + j*16 + lm];
      float p2 = pw2[j*16 + lm];
#pragma unroll
      for (int r = 0; r < 4; r++)
        s[r] += fmaxf(acc[j][r] + cv, 0.f) * p2;
    }
#pragma unroll
    for (int off = 1; off < 16; off <<= 1)
#pragma unroll
      for (int r = 0; r < 4; r++) s[r] += __shfl_xor(s[r], off, 64);
    if (lm == 0) {
      float pb = pb2[0];
#pragma unroll
      for (int r = 0; r < 4; r++) out[e0 + wv*16 + lq*4 + r] = s[r] + pb;
    }
  }
}

// ---------------- launch ----------------
extern "C" void kernel_launch(void* const* d_in, const int* in_sizes, int n_in,
                              void* d_out, int out_size, void* d_ws, size_t ws_size,
                              hipStream_t stream) {
  (void)in_sizes; (void)n_in; (void)out_size; (void)ws_size;
  const int*   h_id   = (const int*)  d_in[0];
  const int*   r_id   = (const int*)  d_in[1];
  const int*   t_id   = (const int*)  d_in[2];
  const float* q      = (const float*)d_in[3];
  const float* ent    = (const float*)d_in[4];
  const float* rel    = (const float*)d_in[6];
  const float* topic  = (const float*)d_in[7];
  const int*   nids   = (const int*)  d_in[8];
  const float* nwts   = (const float*)d_in[9];
  const int*   tids   = (const int*)  d_in[10];
  const float* twts   = (const float*)d_in[11];
  const float* nte    = (const float*)d_in[12];
  const float* mo     = (const float*)d_in[13];
  const float* gsw    = (const float*)d_in[14];
  const float* gsb    = (const float*)d_in[15];
  const float* gmw    = (const float*)d_in[16];
  const float* gmb    = (const float*)d_in[17];
  const float* nh_w   = (const float*)d_in[18];
  const float* nh_b   = (const float*)d_in[19];
  const float* pos_w  = (const float*)d_in[20];
  const float* pos_b  = (const float*)d_in[21];
  const float* st_w   = (const float*)d_in[22];
  const float* st_b   = (const float*)d_in[23];
  const float* gate_w = (const float*)d_in[24];
  const float* gate_b = (const float*)d_in[25];
  const float* pw1    = (const float*)d_in[26];
  const float* pb1    = (const float*)d_in[27];
  const float* pw2    = (const float*)d_in[28];
  const float* pb2    = (const float*)d_in[29];
  float* ws  = (float*)d_ws;
  float* out = (float*)d_out;

  k_prep<<<(Z4 + GTOT + 255)/256, 256, 0, stream>>>(nh_w, pos_w, st_w, pw1, ws);
  k_deg_dde1_adj<<<(NE + 255)/256, 256, 0, stream>>>(h_id, t_id, topic, tids, twts, ws);
  k_pnm<<<NPN_BLOCKS + 2, 256, 0, stream>>>(topic, mo, gsw, gsb, gmw, gmb,
                                            q, gate_w, gate_b, pw1, pb1, ws);
  k_dde2<<<(NE + 255)/256, 256, 0, stream>>>(h_id, t_id, ws);
  k_scale_nme<<<(NTOT*8 + 255)/256, 256, 0, stream>>>(nids, nwts, ws);
  k_edge_mfma<<<NE/64, 256, 0, stream>>>(h_id, r_id, t_id, ent, rel, nte, tids, twts,
                                         nh_b, pos_b, st_b, pw2, pb2, ws, out);
}

// Round 7
// 495.010 us; speedup vs baseline: 1.6046x; 1.6046x over previous
//
#include <hip/hip_runtime.h>
#include <hip/hip_bf16.h>

#define N_TEXT 80000
#define NTOT   100000
#define NE     200000
#define EMB    256
#define HID    256
#define VMOT   17
#define MDIM   64
#define KTOK   4

typedef unsigned short u16;
typedef unsigned int   u32;
typedef short short8 __attribute__((ext_vector_type(8)));
typedef float f32x4 __attribute__((ext_vector_type(4)));

// ---------------- workspace layout (float offsets) ----------------
#define O_INVF 0                    // [NTOT]
#define O_INVR (NTOT)
#define O_POS  (2*NTOT)             // [NTOT*10]
#define O_ADJ  (12*NTOT)            // [289] (pad 512)
#define O_HTB  (12*NTOT + 512)      // u16[17*64] (pad 576 floats)
#define O_GATE (12*NTOT + 1088)
#define O_CVEC (12*NTOT + 1104)
#define O_NME  (12*NTOT + 1360)     // u16[NTOT*64]
#define O_WSW  (O_NME + NTOT*32)    // swizzled bf16 weight blob
#define ZERO_FLOATS (12*NTOT + 512)
#define Z4 (ZERO_FLOATS/4)

// blob layout (u16): [chunk][n-tile j 0..15][lane 0..63][8]
// chunk index: A=0..19, B=20, C=21..30, D=31..38
#define GA 20480
#define GB 1024
#define GC 10240
#define GD 8192
#define GTOT (GA+GB+GC+GD)

__device__ __forceinline__ u16 f2b(float f) {   // fp32 -> bf16 RNE
  unsigned u = __float_as_uint(f);
  return (u16)((u + 0x7fffu + ((u >> 16) & 1u)) >> 16);
}
__device__ __forceinline__ float b2f(u16 v) {
  return __uint_as_float(((unsigned)v) << 16);
}
__device__ __forceinline__ short8 pack8f(const float* f) {
  union { u32 u[4]; short8 s; } o;
#pragma unroll
  for (int i = 0; i < 4; i++) {
    __hip_bfloat162 b = __float22bfloat162_rn(float2{f[2*i], f[2*i+1]});
    o.u[i] = *reinterpret_cast<u32*>(&b);
  }
  return o.s;
}

// ---------------- L1: zero + swizzled weight pack ----------------
__global__ void k_prep(const float* __restrict__ nh_w, const float* __restrict__ pos_w,
                       const float* __restrict__ st_w, const float* __restrict__ pw1,
                       float* __restrict__ ws) {
  int g = blockIdx.x * blockDim.x + threadIdx.x;
  if (g < Z4) { ((float4*)ws)[g] = make_float4(0.f, 0.f, 0.f, 0.f); return; }
  g -= Z4;
  if (g >= GTOT) return;
  int l, phase;
  if (g < GA) { l = g; phase = 0; }
  else if (g < GA + GB) { l = g - GA; phase = 1; }
  else if (g < GA + GB + GC) { l = g - GA - GB; phase = 2; }
  else { l = g - GA - GB - GC; phase = 3; }
  int c = l >> 10, r = l & 1023;
  int w = r >> 8, nt = (r >> 6) & 3, ln = r & 63;
  int col = w*64 + nt*16 + (ln & 15);
  int k0  = c*32 + ((ln >> 4) << 3);
  float f[8];
#pragma unroll
  for (int j = 0; j < 8; j++) {
    int k = k0 + j;
    float v = 0.f;
    if (phase == 0)      v = nh_w[k*256 + col];
    else if (phase == 1) { if (k < 10) v = pos_w[k*256 + col];
                           else if (k >= 16 && k < 26) v = pos_w[(k-6)*256 + col]; }
    else if (phase == 2) v = st_w[k*256 + col];
    else                 v = pw1[(256 + k)*256 + col];
    f[j] = v;
  }
  ((short8*)((u16*)(ws + O_WSW)))[g] = pack8f(f);
}

// ---------------- L2: deg + DDE round-1 + motif adjacency ----------------
__global__ void k_deg_dde1_adj(const int* __restrict__ h_id, const int* __restrict__ t_id,
                               const float* __restrict__ topic,
                               const int* __restrict__ tids, const float* __restrict__ twts,
                               float* __restrict__ ws) {
  __shared__ float sadj[4*304];
  for (int i = threadIdx.x; i < 4*304; i += blockDim.x) sadj[i] = 0.f;
  __syncthreads();
  int wbase = (threadIdx.x >> 6) * 304;
  int e = blockIdx.x * blockDim.x + threadIdx.x;
  if (e < NE) {
    int h = h_id[e], t = t_id[e];
    atomicAdd(&ws[O_INVF + t], 1.0f);
    atomicAdd(&ws[O_INVR + h], 1.0f);
    float hx = topic[2*h], hy = topic[2*h + 1];
    float tx = topic[2*t], ty = topic[2*t + 1];
    if (hx != 0.f) atomicAdd(&ws[O_POS + t*10 + 2], hx);
    if (hy != 0.f) atomicAdd(&ws[O_POS + t*10 + 3], hy);
    if (tx != 0.f) atomicAdd(&ws[O_POS + h*10 + 6], tx);
    if (ty != 0.f) atomicAdd(&ws[O_POS + h*10 + 7], ty);
    int id[KTOK]; float w[KTOK];
#pragma unroll
    for (int k = 0; k < KTOK; k++) { id[k] = tids[e*KTOK + k]; w[k] = twts[e*KTOK + k]; }
#pragma unroll
    for (int i = 0; i < KTOK; i++)
#pragma unroll
      for (int j = 0; j < KTOK; j++) {
        float c = w[i] * w[j];
        if (id[i] > 0 && id[j] > 0 && c > 0.f)
          atomicAdd(&sadj[wbase + id[i]*VMOT + id[j]], c);
      }
  }
  __syncthreads();
  for (int i = threadIdx.x; i < VMOT*VMOT; i += blockDim.x) {
    float v = sadj[i] + sadj[304 + i] + sadj[608 + i] + sadj[912 + i];
    if (v != 0.f) atomicAdd(&ws[O_ADJ + i], v);
  }
}

// ---------------- L3: prep_nodes + motif GNN + gate/cvec ----------------
#define NPN_BLOCKS ((NTOT + 255)/256)
__global__ void k_pnm(const float* __restrict__ topic, const float* __restrict__ mo,
                      const float* __restrict__ gsw, const float* __restrict__ gsb,
                      const float* __restrict__ gmw, const float* __restrict__ gmb,
                      const float* __restrict__ q, const float* __restrict__ gate_w,
                      const float* __restrict__ gate_b, const float* __restrict__ pw1,
                      const float* __restrict__ pb1, float* __restrict__ ws) {
  int t = threadIdx.x;
  if (blockIdx.x < NPN_BLOCKS) {
    int n = blockIdx.x * 256 + t;
    if (n >= NTOT) return;
    float invf = 1.0f / fmaxf(ws[O_INVF + n], 1.0f);
    float invr = 1.0f / fmaxf(ws[O_INVR + n], 1.0f);
    ws[O_INVF + n] = invf;
    ws[O_INVR + n] = invr;
    float* p = &ws[O_POS + n*10];
    p[0] = topic[2*n]; p[1] = topic[2*n + 1];
    p[2] *= invf; p[3] *= invf;
    p[6] *= invr; p[7] *= invr;
  } else if (blockIdx.x == NPN_BLOCKS) {
    __shared__ float A[VMOT*VMOT];
    __shared__ float Bm[VMOT*VMOT];
    __shared__ float inv_row[VMOT];
    __shared__ float smo[VMOT*MDIM];
    __shared__ float sm[VMOT*MDIM];
    for (int i = t; i < VMOT*VMOT; i += 256) A[i] = ws[O_ADJ + i];
    for (int i = t; i < VMOT*MDIM; i += 256) smo[i] = mo[i];
    __syncthreads();
    for (int i = t; i < VMOT*VMOT; i += 256) {
      int r = i / VMOT, c = i % VMOT;
      float v = 0.5f * (A[i] + A[c*VMOT + r]) + (r == c ? 1.f : 0.f);
      if (r == 0 || c == 0) v = (r == 0 && c == 0) ? 1.f : 0.f;
      Bm[i] = v;
    }
    __syncthreads();
    if (t < VMOT) {
      float s = 0.f;
      for (int c = 0; c < VMOT; c++) s += Bm[t*VMOT + c];
      inv_row[t] = 1.f / fmaxf(s, 1e-8f);
    }
    __syncthreads();
    for (int i = t; i < VMOT*MDIM; i += 256) {
      int v = i / MDIM, d = i % MDIM;
      float s = 0.f;
      for (int u = 0; u < VMOT; u++) s += Bm[v*VMOT + u] * smo[u*MDIM + d];
      sm[i] = s * inv_row[v];
    }
    __syncthreads();
    for (int i = t; i < VMOT*MDIM; i += 256) {
      int v = i / MDIM, d = i % MDIM;
      float a = gsb[d] + gmb[d];
      for (int m = 0; m < MDIM; m++)
        a += smo[v*MDIM + m] * gsw[m*MDIM + d] + sm[v*MDIM + m] * gmw[m*MDIM + d];
      ((u16*)(ws + O_HTB))[i] = f2b(smo[i] + fmaxf(a, 0.f));
    }
  } else {
    __shared__ float sq[EMB];
    __shared__ float red[3];
    sq[t] = q[t];
    if (t < 3) red[t] = 0.f;
    __syncthreads();
    float s = pb1[t];
    for (int i = 0; i < EMB; i++) s += sq[i] * pw1[i*HID + t];
    ws[O_CVEC + t] = s;
    atomicAdd(&red[0], sq[t] * gate_w[t*3 + 0]);
    atomicAdd(&red[1], sq[t] * gate_w[t*3 + 1]);
    atomicAdd(&red[2], sq[t] * gate_w[t*3 + 2]);
    __syncthreads();
    if (t == 0) {
      float l0 = red[0] + gate_b[0], l1 = red[1] + gate_b[1], l2 = red[2] + gate_b[2];
      float mx = fmaxf(l0, fmaxf(l1, l2));
      float e0 = expf(l0 - mx), e1 = expf(l1 - mx), e2 = expf(l2 - mx);
      float inv = 1.f / (e0 + e1 + e2);
      ws[O_GATE + 0] = e0 * inv; ws[O_GATE + 1] = e1 * inv; ws[O_GATE + 2] = e2 * inv;
    }
  }
}

// ---------------- L4: DDE round-2 scatter ----------------
__global__ void k_dde2(const int* __restrict__ h_id, const int* __restrict__ t_id,
                       float* __restrict__ ws) {
  int e = blockIdx.x * blockDim.x + threadIdx.x;
  if (e >= NE) return;
  int h = h_id[e], t = t_id[e];
  float a = ws[O_POS + h*10 + 2], b = ws[O_POS + h*10 + 3];
  float c = ws[O_POS + t*10 + 6], d = ws[O_POS + t*10 + 7];
  if (a != 0.f) atomicAdd(&ws[O_POS + t*10 + 4], a);
  if (b != 0.f) atomicAdd(&ws[O_POS + t*10 + 5], b);
  if (c != 0.f) atomicAdd(&ws[O_POS + h*10 + 8], c);
  if (d != 0.f) atomicAdd(&ws[O_POS + h*10 + 9], d);
}

// ---------------- L5: round-2 scale + node motif emb (bf16) ----------------
__global__ void k_scale_nme(const int* __restrict__ nids, const float* __restrict__ nwts,
                            float* __restrict__ ws) {
  __shared__ u16 sht[VMOT*MDIM];
  for (int i = threadIdx.x; i < (VMOT*MDIM)/2; i += blockDim.x)
    ((u32*)sht)[i] = ((const u32*)(ws + O_HTB))[i];
  __syncthreads();
  int gid = blockIdx.x * blockDim.x + threadIdx.x;
  if (gid < NTOT) {
    float invf = ws[O_INVF + gid], invr = ws[O_INVR + gid];
    float* p = &ws[O_POS + gid*10];
    p[4] *= invf; p[5] *= invf;
    p[8] *= invr; p[9] *= invr;
  }
  if (gid >= NTOT * 8) return;
  int n = gid >> 3, d0 = (gid & 7) * 8;
  int4   iv = ((const int4*)nids)[n];
  float4 wv = ((const float4*)nwts)[n];
  float f[8];
#pragma unroll
  for (int j = 0; j < 8; j++) {
    f[j] = wv.x * b2f(sht[iv.x*MDIM + d0 + j]) + wv.y * b2f(sht[iv.y*MDIM + d0 + j])
         + wv.z * b2f(sht[iv.z*MDIM + d0 + j]) + wv.w * b2f(sht[iv.w*MDIM + d0 + j]);
  }
  ((short8*)((u16*)(ws + O_NME)))[gid] = pack8f(f);
}

// ---------------- L6: MFMA edge kernel (r5 structure, fragment-order LDS,
//                     double-buffered sX, 1 barrier/chunk, 4 blocks/CU) ----
// 64 edges x 256 cols per block, waves split N. sX/sF in MFMA-fragment order:
// both staging writes and fragment reads cover 64 distinct 16B chunks of a
// contiguous 1KB window -> conflict-free. LDS = 8KB sX dbuf + 32KB sF = 40960.
__global__ __launch_bounds__(256, 4) void k_edge_mfma(
    const int* __restrict__ h_id, const int* __restrict__ r_id, const int* __restrict__ t_id,
    const float* __restrict__ ent, const float* __restrict__ rel, const float* __restrict__ nte,
    const int* __restrict__ tids, const float* __restrict__ twts,
    const float* __restrict__ nh_b, const float* __restrict__ pos_b,
    const float* __restrict__ st_b, const float* __restrict__ pw2,
    const float* __restrict__ pb2,
    const float* __restrict__ ws, float* __restrict__ out) {
  __shared__ __align__(16) u16 sX[2][2048];   // 8 KB, fragment order per chunk
  __shared__ __align__(16) u16 sF[16384];     // 32 KB, fragment order [c][mt][ln][8]

  const int tid = threadIdx.x;
  const int wv = tid >> 6, ln = tid & 63;
  const int lm = ln & 15, lq = ln >> 4;
  const int cb = wv * 64;
  const int e0 = blockIdx.x * 64;
  const int srow = tid >> 2, sks = tid & 3;                 // staging row / k-seg
  const int xoff = (srow >> 4)*512 + (sks*16 + (srow & 15))*8;  // frag-order slot

  const int   hS = h_id[e0 + srow];
  const int   tS = t_id[e0 + srow];
  const int   rS = r_id[e0 + srow];
  const int4   tivS = ((const int4*)tids)[e0 + srow];
  const float4 twvS = ((const float4*)twts)[e0 + srow];

  const float g0 = ws[O_GATE + 0], g1 = ws[O_GATE + 1], g2 = ws[O_GATE + 2];
  const u16* blob = (const u16*)(ws + O_WSW);
  const u16* nmeb = (const u16*)(ws + O_NME);
  const u16* htb  = (const u16*)(ws + O_HTB);

  f32x4 acc[4][4];
#pragma unroll
  for (int mt = 0; mt < 4; mt++)
#pragma unroll
    for (int nt = 0; nt < 4; nt++) acc[mt][nt] = (f32x4){0.f, 0.f, 0.f, 0.f};

#define MFMA_STEP(buf, bc)                                               \
  { short8 a[4], b[4];                                                   \
    _Pragma("unroll")                                                    \
    for (int nt = 0; nt < 4; nt++)                                       \
      b[nt] = *(const short8*)&blob[(bc)*8192 + wv*2048 + nt*512 + ln*8];\
    _Pragma("unroll")                                                    \
    for (int mt = 0; mt < 4; mt++)                                       \
      a[mt] = *(const short8*)&sX[buf][mt*512 + ln*8];                   \
    _Pragma("unroll")                                                    \
    for (int mt = 0; mt < 4; mt++)                                       \
      _Pragma("unroll")                                                  \
      for (int nt = 0; nt < 4; nt++)                                     \
        acc[mt][nt] = __builtin_amdgcn_mfma_f32_16x16x32_bf16(a[mt], b[nt], acc[mt][nt], 0, 0, 0); }

  // sF epilogue helper index: element (row m=mt*16+lq*4+r, k=col)
  // frag offset = (col>>5)*2048 + mt*512 + ((col>>3)&3)*128 + (lq*4+r)*8 + (col&7)

  float4 fa, fb; short8 xs;      // staging prefetch regs
  auto loadA = [&](int c) {
    int kk = c*32 + sks*8;
    if (kk < 512) {
      int node = (kk < 256) ? hS : tS;
      int k2 = kk & 255;
      const float* src = (node < N_TEXT) ? &ent[(size_t)node*256 + k2] : &nte[k2];
      fa = *(const float4*)src; fb = *(const float4*)(src + 4);
    } else {
      int node = (kk < 576) ? hS : tS;
      xs = *(const short8*)&nmeb[(size_t)node*64 + ((kk - 512) & 63)];
    }
  };
  auto storeA = [&](int buf, int c) {
    if (c < 16) {
      float f[8] = {fa.x, fa.y, fa.z, fa.w, fb.x, fb.y, fb.z, fb.w};
      *(short8*)&sX[buf][xoff] = pack8f(f);
    } else {
      *(short8*)&sX[buf][xoff] = xs;
    }
  };
  auto loadC = [&](int c) {
    int kk = c*32 + sks*8;
    if (kk < 256) {
      const float* src = &rel[(size_t)rS*256 + kk];
      fa = *(const float4*)src; fb = *(const float4*)(src + 4);
    } else {
      int d0 = kk - 256;
      short8 h0 = *(const short8*)&htb[tivS.x*64 + d0];
      short8 h1 = *(const short8*)&htb[tivS.y*64 + d0];
      short8 h2 = *(const short8*)&htb[tivS.z*64 + d0];
      short8 h3 = *(const short8*)&htb[tivS.w*64 + d0];
      float f[8];
#pragma unroll
      for (int j = 0; j < 8; j++)
        f[j] = twvS.x * b2f((u16)h0[j]) + twvS.y * b2f((u16)h1[j])
             + twvS.z * b2f((u16)h2[j]) + twvS.w * b2f((u16)h3[j]);
      xs = pack8f(f);
    }
  };
  auto storeC = [&](int buf, int c) {
    if (c < 8) {
      float f[8] = {fa.x, fa.y, fa.z, fa.w, fb.x, fb.y, fb.z, fb.w};
      *(short8*)&sX[buf][xoff] = pack8f(f);
    } else {
      *(short8*)&sX[buf][xoff] = xs;
    }
  };

  // ======== phase A: K=640, chunks 0..19 ========
  loadA(0); storeA(0, 0);
  for (int c = 0; c < 20; c++) {
    __syncthreads();
    if (c < 19) loadA(c + 1);
    MFMA_STEP(c & 1, c);
    if (c < 19) {
      storeA((c + 1) & 1, c + 1);
    } else {
      // stage phase-B pos chunk into buf0 (chunk 20, parity 0)
      float f[8];
#pragma unroll
      for (int j = 0; j < 8; j++) {
        int kk = sks*8 + j;
        float v = 0.f;
        if (kk < 10) v = ws[O_POS + (size_t)hS*10 + kk];
        else if (kk >= 16 && kk < 26) v = ws[O_POS + (size_t)tS*10 + kk - 16];
        f[j] = v;
      }
      *(short8*)&sX[0][xoff] = pack8f(f);
    }
  }
  // epilogue A: sF = g0*relu(acc + nh_b)  (fragment order)
#pragma unroll
  for (int nt = 0; nt < 4; nt++) {
    int col = cb + nt*16 + lm;
    float bb = nh_b[col];
    int base = (col >> 5)*2048 + ((col >> 3) & 3)*128 + (col & 7);
#pragma unroll
    for (int mt = 0; mt < 4; mt++)
#pragma unroll
      for (int r = 0; r < 4; r++) {
        sF[base + mt*512 + (lq*4 + r)*8] = f2b(g0 * fmaxf(acc[mt][nt][r] + bb, 0.f));
        acc[mt][nt][r] = 0.f;
      }
  }

  // ======== phase B: chunk 20 ========
  __syncthreads();
  MFMA_STEP(0, 20);
  loadC(0);                       // prefetch C chunk 0 (rel)
#pragma unroll
  for (int nt = 0; nt < 4; nt++) {
    int col = cb + nt*16 + lm;
    float bb = pos_b[col];
    int base = (col >> 5)*2048 + ((col >> 3) & 3)*128 + (col & 7);
#pragma unroll
    for (int mt = 0; mt < 4; mt++)
#pragma unroll
      for (int r = 0; r < 4; r++) {
        u16* p = &sF[base + mt*512 + (lq*4 + r)*8];
        *p = f2b(b2f(*p) + g1 * fmaxf(acc[mt][nt][r] + bb, 0.f));
        acc[mt][nt][r] = 0.f;
      }
  }
  storeC(1, 0);                   // C chunk 0 -> buf1 (chunk 21, parity 1)

  // ======== phase C: chunks 21..30 ========
  for (int c = 0; c < 10; c++) {
    __syncthreads();
    if (c < 9) loadC(c + 1);
    MFMA_STEP((c + 1) & 1, 21 + c);
    if (c < 9) storeC(c & 1, c + 1);
  }
  // epilogue C
#pragma unroll
  for (int nt = 0; nt < 4; nt++) {
    int col = cb + nt*16 + lm;
    float bb = st_b[col];
    int base = (col >> 5)*2048 + ((col >> 3) & 3)*128 + (col & 7);
#pragma unroll
    for (int mt = 0; mt < 4; mt++)
#pragma unroll
      for (int r = 0; r < 4; r++) {
        u16* p = &sF[base + mt*512 + (lq*4 + r)*8];
        *p = f2b(b2f(*p) + g2 * fmaxf(acc[mt][nt][r] + bb, 0.f));
        acc[mt][nt][r] = 0.f;
      }
  }

  __syncthreads();   // sF complete (all waves)

  // ======== phase D: hidden = fused @ pw1[256:512], chunks 31..38 ========
#pragma unroll 2
  for (int c = 0; c < 8; c++) {
    short8 a[4], b[4];
#pragma unroll
    for (int nt = 0; nt < 4; nt++)
      b[nt] = *(const short8*)&blob[(31 + c)*8192 + wv*2048 + nt*512 + ln*8];
#pragma unroll
    for (int mt = 0; mt < 4; mt++)
      a[mt] = *(const short8*)&sF[c*2048 + mt*512 + ln*8];
#pragma unroll
    for (int mt = 0; mt < 4; mt++)
#pragma unroll
      for (int nt = 0; nt < 4; nt++)
        acc[mt][nt] = __builtin_amdgcn_mfma_f32_16x16x32_bf16(a[mt], b[nt], acc[mt][nt], 0, 0, 0);
  }

  // ======== epilogue: out = relu(hidden + cvec) @ pw2 + pb2 ========
  __syncthreads();                 // all sF reads done; reuse sF[0:64] as fp32 buf
  float* sOut = (float*)sF;
  if (tid < 64) sOut[tid] = 0.f;
  __syncthreads();
  {
    float cv[4], p2[4];
#pragma unroll
    for (int nt = 0; nt < 4; nt++) {
      int col = cb + nt*16 + lm;
      cv[nt] = ws[O_CVEC + col];
      p2[nt] = pw2[col];
    }
#pragma unroll
    for (int mt = 0; mt < 4; mt++)
#pragma unroll
      for (int r = 0; r < 4; r++) {
        float s = 0.f;
#pragma unroll
        for (int nt = 0; nt < 4; nt++)
          s += fmaxf(acc[mt][nt][r] + cv[nt], 0.f) * p2[nt];
#pragma unroll
        for (int off = 1; off < 16; off <<= 1)
          s += __shfl_xor(s, off, 64);
        if (lm == 0) atomicAdd(&sOut[mt*16 + lq*4 + r], s);
      }
  }
  __syncthreads();
  if (tid < 64) out[e0 + tid] = sOut[tid] + pb2[0];
#undef MFMA_STEP
}

// ---------------- launch ----------------
extern "C" void kernel_launch(void* const* d_in, const int* in_sizes, int n_in,
                              void* d_out, int out_size, void* d_ws, size_t ws_size,
                              hipStream_t stream) {
  (void)in_sizes; (void)n_in; (void)out_size; (void)ws_size;
  const int*   h_id   = (const int*)  d_in[0];
  const int*   r_id   = (const int*)  d_in[1];
  const int*   t_id   = (const int*)  d_in[2];
  const float* q      = (const float*)d_in[3];
  const float* ent    = (const float*)d_in[4];
  const float* rel    = (const float*)d_in[6];
  const float* topic  = (const float*)d_in[7];
  const int*   nids   = (const int*)  d_in[8];
  const float* nwts   = (const float*)d_in[9];
  const int*   tids   = (const int*)  d_in[10];
  const float* twts   = (const float*)d_in[11];
  const float* nte    = (const float*)d_in[12];
  const float* mo     = (const float*)d_in[13];
  const float* gsw    = (const float*)d_in[14];
  const float* gsb    = (const float*)d_in[15];
  const float* gmw    = (const float*)d_in[16];
  const float* gmb    = (const float*)d_in[17];
  const float* nh_w   = (const float*)d_in[18];
  const float* nh_b   = (const float*)d_in[19];
  const float* pos_w  = (const float*)d_in[20];
  const float* pos_b  = (const float*)d_in[21];
  const float* st_w   = (const float*)d_in[22];
  const float* st_b   = (const float*)d_in[23];
  const float* gate_w = (const float*)d_in[24];
  const float* gate_b = (const float*)d_in[25];
  const float* pw1    = (const float*)d_in[26];
  const float* pb1    = (const float*)d_in[27];
  const float* pw2    = (const float*)d_in[28];
  const float* pb2    = (const float*)d_in[29];
  float* ws  = (float*)d_ws;
  float* out = (float*)d_out;

  k_prep<<<(Z4 + GTOT + 255)/256, 256, 0, stream>>>(nh_w, pos_w, st_w, pw1, ws);
  k_deg_dde1_adj<<<(NE + 255)/256, 256, 0, stream>>>(h_id, t_id, topic, tids, twts, ws);
  k_pnm<<<NPN_BLOCKS + 2, 256, 0, stream>>>(topic, mo, gsw, gsb, gmw, gmb,
                                            q, gate_w, gate_b, pw1, pb1, ws);
  k_dde2<<<(NE + 255)/256, 256, 0, stream>>>(h_id, t_id, ws);
  k_scale_nme<<<(NTOT*8 + 255)/256, 256, 0, stream>>>(nids, nwts, ws);
  k_edge_mfma<<<NE/64, 256, 0, stream>>>(h_id, r_id, t_id, ent, rel, nte, tids, twts,
                                         nh_b, pos_b, st_b, pw2, pb2, ws, out);
}

// Round 8
// 439.344 us; speedup vs baseline: 1.8079x; 1.1267x over previous
//
#include <hip/hip_runtime.h>
#include <hip/hip_bf16.h>

#define N_TEXT 80000
#define NTOT   100000
#define NE     200000
#define EMB    256
#define HID    256
#define VMOT   17
#define MDIM   64
#define KTOK   4

typedef unsigned short u16;
typedef unsigned int   u32;
typedef short short8 __attribute__((ext_vector_type(8)));
typedef float f32x4 __attribute__((ext_vector_type(4)));

// ---------------- workspace layout (float offsets) ----------------
#define O_INVF 0                    // [NTOT]
#define O_INVR (NTOT)
#define O_POS  (2*NTOT)             // [NTOT*10]
#define O_ADJ  (12*NTOT)            // [289] (pad 512)
#define O_HTB  (12*NTOT + 512)      // u16[17*64] (pad 576 floats)
#define O_GATE (12*NTOT + 1088)
#define O_CVEC (12*NTOT + 1104)
#define O_NME  (12*NTOT + 1360)     // u16[NTOT*64]
#define O_WSW  (O_NME + NTOT*32)    // swizzled bf16 weight blob
#define ZERO_FLOATS (12*NTOT + 512)

// blob layout (u16): [chunk][n-tile j 0..15][lane 0..63][8]
// staged chunks: A=0..19 (K=640), B=20 (K=32), C=21..30 (K=320); D=31..38
#define GA 20480
#define GB 1024
#define GC 10240
#define GD 8192
#define GTOT (GA+GB+GC+GD)
#define PREPB ((GTOT + 255)/256)
#define EDGEB ((NE + 255)/256)

__device__ __forceinline__ u16 f2b(float f) {   // fp32 -> bf16 RNE
  unsigned u = __float_as_uint(f);
  return (u16)((u + 0x7fffu + ((u >> 16) & 1u)) >> 16);
}
__device__ __forceinline__ float b2f(u16 v) {
  return __uint_as_float(((unsigned)v) << 16);
}
__device__ __forceinline__ short8 pack8f(const float* f) {
  union { u32 u[4]; short8 s; } o;
#pragma unroll
  for (int i = 0; i < 4; i++) {
    __hip_bfloat162 b = __float22bfloat162_rn(float2{f[2*i], f[2*i+1]});
    o.u[i] = *reinterpret_cast<u32*>(&b);
  }
  return o.s;
}

// ---------------- L1: weight pack + deg/DDE1/adj (independent halves) ------
__global__ void k_init(const float* __restrict__ nh_w, const float* __restrict__ pos_w,
                       const float* __restrict__ st_w, const float* __restrict__ pw1,
                       const int* __restrict__ h_id, const int* __restrict__ t_id,
                       const float* __restrict__ topic,
                       const int* __restrict__ tids, const float* __restrict__ twts,
                       float* __restrict__ ws) {
  __shared__ float sadj[4*304];
  if (blockIdx.x < PREPB) {
    int g = blockIdx.x * 256 + threadIdx.x;
    if (g >= GTOT) return;
    int l, phase;
    if (g < GA) { l = g; phase = 0; }
    else if (g < GA + GB) { l = g - GA; phase = 1; }
    else if (g < GA + GB + GC) { l = g - GA - GB; phase = 2; }
    else { l = g - GA - GB - GC; phase = 3; }
    int c = l >> 10, r = l & 1023;
    int w = r >> 8, nt = (r >> 6) & 3, ln = r & 63;
    int col = w*64 + nt*16 + (ln & 15);
    int k0  = c*32 + ((ln >> 4) << 3);
    float f[8];
#pragma unroll
    for (int j = 0; j < 8; j++) {
      int k = k0 + j;
      float v = 0.f;
      if (phase == 0)      v = nh_w[k*256 + col];
      else if (phase == 1) { if (k < 10) v = pos_w[k*256 + col];
                             else if (k >= 16 && k < 26) v = pos_w[(k-6)*256 + col]; }
      else if (phase == 2) v = st_w[k*256 + col];
      else                 v = pw1[(256 + k)*256 + col];
      f[j] = v;
    }
    ((short8*)((u16*)(ws + O_WSW)))[g] = pack8f(f);
  } else {
    for (int i = threadIdx.x; i < 4*304; i += blockDim.x) sadj[i] = 0.f;
    __syncthreads();
    int wbase = (threadIdx.x >> 6) * 304;
    int e = (blockIdx.x - PREPB) * 256 + threadIdx.x;
    if (e < NE) {
      int h = h_id[e], t = t_id[e];
      atomicAdd(&ws[O_INVF + t], 1.0f);
      atomicAdd(&ws[O_INVR + h], 1.0f);
      float hx = topic[2*h], hy = topic[2*h + 1];
      float tx = topic[2*t], ty = topic[2*t + 1];
      if (hx != 0.f) atomicAdd(&ws[O_POS + t*10 + 2], hx);
      if (hy != 0.f) atomicAdd(&ws[O_POS + t*10 + 3], hy);
      if (tx != 0.f) atomicAdd(&ws[O_POS + h*10 + 6], tx);
      if (ty != 0.f) atomicAdd(&ws[O_POS + h*10 + 7], ty);
      int id[KTOK]; float w[KTOK];
#pragma unroll
      for (int k = 0; k < KTOK; k++) { id[k] = tids[e*KTOK + k]; w[k] = twts[e*KTOK + k]; }
#pragma unroll
      for (int i = 0; i < KTOK; i++)
#pragma unroll
        for (int j = 0; j < KTOK; j++) {
          float c = w[i] * w[j];
          if (id[i] > 0 && id[j] > 0 && c > 0.f)
            atomicAdd(&sadj[wbase + id[i]*VMOT + id[j]], c);
        }
    }
    __syncthreads();
    for (int i = threadIdx.x; i < VMOT*VMOT; i += blockDim.x) {
      float v = sadj[i] + sadj[304 + i] + sadj[608 + i] + sadj[912 + i];
      if (v != 0.f) atomicAdd(&ws[O_ADJ + i], v);
    }
  }
}

// ---------------- L2: prep_nodes + motif GNN + gate/cvec ----------------
#define NPN_BLOCKS ((NTOT + 255)/256)
__global__ void k_pnm(const float* __restrict__ topic, const float* __restrict__ mo,
                      const float* __restrict__ gsw, const float* __restrict__ gsb,
                      const float* __restrict__ gmw, const float* __restrict__ gmb,
                      const float* __restrict__ q, const float* __restrict__ gate_w,
                      const float* __restrict__ gate_b, const float* __restrict__ pw1,
                      const float* __restrict__ pb1, float* __restrict__ ws) {
  int t = threadIdx.x;
  if (blockIdx.x < NPN_BLOCKS) {
    int n = blockIdx.x * 256 + t;
    if (n >= NTOT) return;
    float invf = 1.0f / fmaxf(ws[O_INVF + n], 1.0f);
    float invr = 1.0f / fmaxf(ws[O_INVR + n], 1.0f);
    ws[O_INVF + n] = invf;
    ws[O_INVR + n] = invr;
    float* p = &ws[O_POS + n*10];
    p[0] = topic[2*n]; p[1] = topic[2*n + 1];
    p[2] *= invf; p[3] *= invf;
    p[6] *= invr; p[7] *= invr;
  } else if (blockIdx.x == NPN_BLOCKS) {
    __shared__ float A[VMOT*VMOT];
    __shared__ float Bm[VMOT*VMOT];
    __shared__ float inv_row[VMOT];
    __shared__ float smo[VMOT*MDIM];
    __shared__ float sm[VMOT*MDIM];
    for (int i = t; i < VMOT*VMOT; i += 256) A[i] = ws[O_ADJ + i];
    for (int i = t; i < VMOT*MDIM; i += 256) smo[i] = mo[i];
    __syncthreads();
    for (int i = t; i < VMOT*VMOT; i += 256) {
      int r = i / VMOT, c = i % VMOT;
      float v = 0.5f * (A[i] + A[c*VMOT + r]) + (r == c ? 1.f : 0.f);
      if (r == 0 || c == 0) v = (r == 0 && c == 0) ? 1.f : 0.f;
      Bm[i] = v;
    }
    __syncthreads();
    if (t < VMOT) {
      float s = 0.f;
      for (int c = 0; c < VMOT; c++) s += Bm[t*VMOT + c];
      inv_row[t] = 1.f / fmaxf(s, 1e-8f);
    }
    __syncthreads();
    for (int i = t; i < VMOT*MDIM; i += 256) {
      int v = i / MDIM, d = i % MDIM;
      float s = 0.f;
      for (int u = 0; u < VMOT; u++) s += Bm[v*VMOT + u] * smo[u*MDIM + d];
      sm[i] = s * inv_row[v];
    }
    __syncthreads();
    for (int i = t; i < VMOT*MDIM; i += 256) {
      int v = i / MDIM, d = i % MDIM;
      float a = gsb[d] + gmb[d];
      for (int m = 0; m < MDIM; m++)
        a += smo[v*MDIM + m] * gsw[m*MDIM + d] + sm[v*MDIM + m] * gmw[m*MDIM + d];
      ((u16*)(ws + O_HTB))[i] = f2b(smo[i] + fmaxf(a, 0.f));
    }
  } else {
    __shared__ float sq[EMB];
    __shared__ float red[3];
    sq[t] = q[t];
    if (t < 3) red[t] = 0.f;
    __syncthreads();
    float s = pb1[t];
    for (int i = 0; i < EMB; i++) s += sq[i] * pw1[i*HID + t];
    ws[O_CVEC + t] = s;
    atomicAdd(&red[0], sq[t] * gate_w[t*3 + 0]);
    atomicAdd(&red[1], sq[t] * gate_w[t*3 + 1]);
    atomicAdd(&red[2], sq[t] * gate_w[t*3 + 2]);
    __syncthreads();
    if (t == 0) {
      float l0 = red[0] + gate_b[0], l1 = red[1] + gate_b[1], l2 = red[2] + gate_b[2];
      float mx = fmaxf(l0, fmaxf(l1, l2));
      float e0 = expf(l0 - mx), e1 = expf(l1 - mx), e2 = expf(l2 - mx);
      float inv = 1.f / (e0 + e1 + e2);
      ws[O_GATE + 0] = e0 * inv; ws[O_GATE + 1] = e1 * inv; ws[O_GATE + 2] = e2 * inv;
    }
  }
}

// ---------------- L3: DDE round-2 scatter ----------------
__global__ void k_dde2(const int* __restrict__ h_id, const int* __restrict__ t_id,
                       float* __restrict__ ws) {
  int e = blockIdx.x * blockDim.x + threadIdx.x;
  if (e >= NE) return;
  int h = h_id[e], t = t_id[e];
  float a = ws[O_POS + h*10 + 2], b = ws[O_POS + h*10 + 3];
  float c = ws[O_POS + t*10 + 6], d = ws[O_POS + t*10 + 7];
  if (a != 0.f) atomicAdd(&ws[O_POS + t*10 + 4], a);
  if (b != 0.f) atomicAdd(&ws[O_POS + t*10 + 5], b);
  if (c != 0.f) atomicAdd(&ws[O_POS + h*10 + 8], c);
  if (d != 0.f) atomicAdd(&ws[O_POS + h*10 + 9], d);
}

// ---------------- L4: round-2 scale + node motif emb (bf16) ----------------
__global__ void k_scale_nme(const int* __restrict__ nids, const float* __restrict__ nwts,
                            float* __restrict__ ws) {
  __shared__ u16 sht[VMOT*MDIM];
  for (int i = threadIdx.x; i < (VMOT*MDIM)/2; i += blockDim.x)
    ((u32*)sht)[i] = ((const u32*)(ws + O_HTB))[i];
  __syncthreads();
  int gid = blockIdx.x * blockDim.x + threadIdx.x;
  if (gid < NTOT) {
    float invf = ws[O_INVF + gid], invr = ws[O_INVR + gid];
    float* p = &ws[O_POS + gid*10];
    p[4] *= invf; p[5] *= invf;
    p[8] *= invr; p[9] *= invr;
  }
  if (gid >= NTOT * 8) return;
  int n = gid >> 3, d0 = (gid & 7) * 8;
  int4   iv = ((const int4*)nids)[n];
  float4 wv = ((const float4*)nwts)[n];
  float f[8];
#pragma unroll
  for (int j = 0; j < 8; j++) {
    f[j] = wv.x * b2f(sht[iv.x*MDIM + d0 + j]) + wv.y * b2f(sht[iv.y*MDIM + d0 + j])
         + wv.z * b2f(sht[iv.z*MDIM + d0 + j]) + wv.w * b2f(sht[iv.w*MDIM + d0 + j]);
  }
  ((short8*)((u16*)(ws + O_NME)))[gid] = pack8f(f);
}

// ---------------- L5: MFMA edge kernel — deep software pipeline ------------
// 64 edges x 256 cols/block, waves split N. Fully-unrolled staged loop:
// gather(c+2) issued at iter c (2-period cover), B(c+1) reg-prefetched at
// iter c (MFMAs never wait on fresh loads). 1 barrier/chunk.
__global__ __launch_bounds__(256, 3) void k_edge_mfma(
    const int* __restrict__ h_id, const int* __restrict__ r_id, const int* __restrict__ t_id,
    const float* __restrict__ ent, const float* __restrict__ rel, const float* __restrict__ nte,
    const int* __restrict__ tids, const float* __restrict__ twts,
    const float* __restrict__ nh_b, const float* __restrict__ pos_b,
    const float* __restrict__ st_b, const float* __restrict__ pw2,
    const float* __restrict__ pb2,
    const float* __restrict__ ws, float* __restrict__ out) {
  __shared__ __align__(16) u16 sX[2][2048];   // 8 KB, fragment-order chunks
  __shared__ __align__(16) u16 sF[16384];     // 32 KB, fragment order

  const int tid = threadIdx.x;
  const int wv = tid >> 6, ln = tid & 63;
  const int lm = ln & 15, lq = ln >> 4;
  const int cb = wv * 64;
  const int e0 = blockIdx.x * 64;
  const int srow = tid >> 2, sks = tid & 3;
  const int xoff = (srow >> 4)*512 + (sks*16 + (srow & 15))*8;

  const int   hS = h_id[e0 + srow];
  const int   tS = t_id[e0 + srow];
  const int   rS = r_id[e0 + srow];
  const int4   tivS = ((const int4*)tids)[e0 + srow];
  const float4 twvS = ((const float4*)twts)[e0 + srow];

  const float g0 = ws[O_GATE + 0], g1 = ws[O_GATE + 1], g2 = ws[O_GATE + 2];
  const u16* blob = (const u16*)(ws + O_WSW);
  const u16* nmeb = (const u16*)(ws + O_NME);
  const u16* htb  = (const u16*)(ws + O_HTB);

  f32x4 acc[4][4];
#pragma unroll
  for (int mt = 0; mt < 4; mt++)
#pragma unroll
    for (int nt = 0; nt < 4; nt++) acc[mt][nt] = (f32x4){0.f, 0.f, 0.f, 0.f};

  float4 gfa[2], gfb[2]; short8 gxs[2];     // gather reg sets (by chunk parity)
  short8 breg[2][4];                        // B frags (by chunk parity)

  auto gatherX = [&](int k) {               // issue gathers for staged chunk k
    int p = k & 1;
    if (k < 16) {                           // ent fp32 rows (deferred pack)
      int kk = k*32 + sks*8;
      int node = (kk < 256) ? hS : tS;
      int k2 = kk & 255;
      const float* src = (node < N_TEXT) ? &ent[(size_t)node*256 + k2] : &nte[k2];
      gfa[p] = *(const float4*)src; gfb[p] = *(const float4*)(src + 4);
    } else if (k < 20) {                    // nme bf16 (pure load)
      int kk = k*32 + sks*8;
      int node = (kk < 576) ? hS : tS;
      gxs[p] = *(const short8*)&nmeb[(size_t)node*64 + ((kk - 512) & 63)];
    } else if (k == 20) {                   // pos (eager pack, rare)
      float f[8];
#pragma unroll
      for (int j = 0; j < 8; j++) {
        int kk = sks*8 + j;
        float v = 0.f;
        if (kk < 10) v = ws[O_POS + (size_t)hS*10 + kk];
        else if (kk >= 16 && kk < 26) v = ws[O_POS + (size_t)tS*10 + kk - 16];
        f[j] = v;
      }
      gxs[p] = pack8f(f);
    } else if (k < 29) {                    // rel fp32 (deferred pack)
      int kk = (k - 21)*32 + sks*8;
      const float* src = &rel[(size_t)rS*256 + kk];
      gfa[p] = *(const float4*)src; gfb[p] = *(const float4*)(src + 4);
    } else {                                // ht-combo (eager, rare)
      int d0 = (k - 21)*32 + sks*8 - 256;
      short8 h0 = *(const short8*)&htb[tivS.x*64 + d0];
      short8 h1 = *(const short8*)&htb[tivS.y*64 + d0];
      short8 h2 = *(const short8*)&htb[tivS.z*64 + d0];
      short8 h3 = *(const short8*)&htb[tivS.w*64 + d0];
      float f[8];
#pragma unroll
      for (int j = 0; j < 8; j++)
        f[j] = twvS.x * b2f((u16)h0[j]) + twvS.y * b2f((u16)h1[j])
             + twvS.z * b2f((u16)h2[j]) + twvS.w * b2f((u16)h3[j]);
      gxs[p] = pack8f(f);
    }
  };
  auto storeX = [&](int k) {
    int p = k & 1;
    if (k < 16 || (k >= 21 && k < 29)) {
      float f[8] = {gfa[p].x, gfa[p].y, gfa[p].z, gfa[p].w,
                    gfb[p].x, gfb[p].y, gfb[p].z, gfb[p].w};
      *(short8*)&sX[p][xoff] = pack8f(f);
    } else {
      *(short8*)&sX[p][xoff] = gxs[p];
    }
  };
  auto bload = [&](int bc, int p) {
#pragma unroll
    for (int nt = 0; nt < 4; nt++)
      breg[p][nt] = *(const short8*)&blob[(size_t)bc*8192 + wv*2048 + nt*512 + ln*8];
  };
  auto epi_store = [&](const float* __restrict__ bias, float g) {  // first write
#pragma unroll
    for (int nt = 0; nt < 4; nt++) {
      int col = cb + nt*16 + lm;
      float bb = bias[col];
      int base = (col >> 5)*2048 + ((col >> 3) & 3)*128 + (col & 7);
#pragma unroll
      for (int mt = 0; mt < 4; mt++)
#pragma unroll
        for (int r = 0; r < 4; r++) {
          sF[base + mt*512 + (lq*4 + r)*8] = f2b(g * fmaxf(acc[mt][nt][r] + bb, 0.f));
          acc[mt][nt][r] = 0.f;
        }
    }
  };
  auto epi_rmw = [&](const float* __restrict__ bias, float g) {
#pragma unroll
    for (int nt = 0; nt < 4; nt++) {
      int col = cb + nt*16 + lm;
      float bb = bias[col];
      int base = (col >> 5)*2048 + ((col >> 3) & 3)*128 + (col & 7);
#pragma unroll
      for (int mt = 0; mt < 4; mt++)
#pragma unroll
        for (int r = 0; r < 4; r++) {
          u16* p = &sF[base + mt*512 + (lq*4 + r)*8];
          *p = f2b(b2f(*p) + g * fmaxf(acc[mt][nt][r] + bb, 0.f));
          acc[mt][nt][r] = 0.f;
        }
    }
  };

  // ---- pipeline prologue ----
  gatherX(0); gatherX(1);
  bload(0, 0);
  storeX(0);

  // ---- staged chunks 0..30 (phases A, B, C) ----
#pragma unroll
  for (int c = 0; c < 31; c++) {
    __syncthreads();
    {
      short8 a[4];
#pragma unroll
      for (int mt = 0; mt < 4; mt++)
        a[mt] = *(const short8*)&sX[c & 1][mt*512 + ln*8];
#pragma unroll
      for (int mt = 0; mt < 4; mt++)
#pragma unroll
        for (int nt = 0; nt < 4; nt++)
          acc[mt][nt] = __builtin_amdgcn_mfma_f32_16x16x32_bf16(
              a[mt], breg[c & 1][nt], acc[mt][nt], 0, 0, 0);
    }
    if (c < 30) storeX(c + 1);          // data gathered 2 iters ago
    bload(c + 1, (c + 1) & 1);          // B for next chunk (c+1 <= 31)
    if (c < 29) gatherX(c + 2);         // issue next gather
    if (c == 19) epi_store(nh_b, g0);
    if (c == 20) epi_rmw(pos_b, g1);
    if (c == 30) epi_rmw(st_b, g2);
  }

  __syncthreads();   // sF complete across waves

  // ---- phase D: hidden = fused @ pw1[256:512], blob chunks 31..38 ----
#pragma unroll
  for (int c = 0; c < 8; c++) {
    short8 a[4];
#pragma unroll
    for (int mt = 0; mt < 4; mt++)
      a[mt] = *(const short8*)&sF[c*2048 + mt*512 + ln*8];
#pragma unroll
    for (int mt = 0; mt < 4; mt++)
#pragma unroll
      for (int nt = 0; nt < 4; nt++)
        acc[mt][nt] = __builtin_amdgcn_mfma_f32_16x16x32_bf16(
            a[mt], breg[(31 + c) & 1][nt], acc[mt][nt], 0, 0, 0);
    if (c < 7) bload(32 + c, (32 + c) & 1);
  }

  // ---- epilogue: out = relu(hidden + cvec) @ pw2 + pb2 ----
  __syncthreads();                 // all sF reads done; reuse as fp32 buf
  float* sOut = (float*)sF;
  if (tid < 64) sOut[tid] = 0.f;
  __syncthreads();
  {
    float cv[4], p2[4];
#pragma unroll
    for (int nt = 0; nt < 4; nt++) {
      int col = cb + nt*16 + lm;
      cv[nt] = ws[O_CVEC + col];
      p2[nt] = pw2[col];
    }
#pragma unroll
    for (int mt = 0; mt < 4; mt++)
#pragma unroll
      for (int r = 0; r < 4; r++) {
        float s = 0.f;
#pragma unroll
        for (int nt = 0; nt < 4; nt++)
          s += fmaxf(acc[mt][nt][r] + cv[nt], 0.f) * p2[nt];
#pragma unroll
        for (int off = 1; off < 16; off <<= 1)
          s += __shfl_xor(s, off, 64);
        if (lm == 0) atomicAdd(&sOut[mt*16 + lq*4 + r], s);
      }
  }
  __syncthreads();
  if (tid < 64) out[e0 + tid] = sOut[tid] + pb2[0];
}

// ---------------- launch ----------------
extern "C" void kernel_launch(void* const* d_in, const int* in_sizes, int n_in,
                              void* d_out, int out_size, void* d_ws, size_t ws_size,
                              hipStream_t stream) {
  (void)in_sizes; (void)n_in; (void)out_size; (void)ws_size;
  const int*   h_id   = (const int*)  d_in[0];
  const int*   r_id   = (const int*)  d_in[1];
  const int*   t_id   = (const int*)  d_in[2];
  const float* q      = (const float*)d_in[3];
  const float* ent    = (const float*)d_in[4];
  const float* rel    = (const float*)d_in[6];
  const float* topic  = (const float*)d_in[7];
  const int*   nids   = (const int*)  d_in[8];
  const float* nwts   = (const float*)d_in[9];
  const int*   tids   = (const int*)  d_in[10];
  const float* twts   = (const float*)d_in[11];
  const float* nte    = (const float*)d_in[12];
  const float* mo     = (const float*)d_in[13];
  const float* gsw    = (const float*)d_in[14];
  const float* gsb    = (const float*)d_in[15];
  const float* gmw    = (const float*)d_in[16];
  const float* gmb    = (const float*)d_in[17];
  const float* nh_w   = (const float*)d_in[18];
  const float* nh_b   = (const float*)d_in[19];
  const float* pos_w  = (const float*)d_in[20];
  const float* pos_b  = (const float*)d_in[21];
  const float* st_w   = (const float*)d_in[22];
  const float* st_b   = (const float*)d_in[23];
  const float* gate_w = (const float*)d_in[24];
  const float* gate_b = (const float*)d_in[25];
  const float* pw1    = (const float*)d_in[26];
  const float* pb1    = (const float*)d_in[27];
  const float* pw2    = (const float*)d_in[28];
  const float* pb2    = (const float*)d_in[29];
  float* ws  = (float*)d_ws;
  float* out = (float*)d_out;

  hipMemsetAsync(ws, 0, (size_t)ZERO_FLOATS * sizeof(float), stream);
  k_init<<<PREPB + EDGEB, 256, 0, stream>>>(nh_w, pos_w, st_w, pw1,
                                            h_id, t_id, topic, tids, twts, ws);
  k_pnm<<<NPN_BLOCKS + 2, 256, 0, stream>>>(topic, mo, gsw, gsb, gmw, gmb,
                                            q, gate_w, gate_b, pw1, pb1, ws);
  k_dde2<<<(NE + 255)/256, 256, 0, stream>>>(h_id, t_id, ws);
  k_scale_nme<<<(NTOT*8 + 255)/256, 256, 0, stream>>>(nids, nwts, ws);
  k_edge_mfma<<<NE/64, 256, 0, stream>>>(h_id, r_id, t_id, ent, rel, nte, tids, twts,
                                         nh_b, pos_b, st_b, pw2, pb2, ws, out);
}